// Round 1
// baseline (32487.976 us; speedup 1.0000x reference)
//
#include <hip/hip_runtime.h>
#include <hip/hip_bf16.h>

typedef unsigned short u16;
typedef __attribute__((ext_vector_type(8))) short bf16x8;  // 8 bf16 (4 VGPRs)
typedef __attribute__((ext_vector_type(4))) float f32x4;   // MFMA accumulator

#define SCOPE_AGENT __HIP_MEMORY_SCOPE_AGENT

__device__ __forceinline__ float bf2f(u16 u){
  union { unsigned int i; float f; } v; v.i = ((unsigned int)u) << 16; return v.f;
}
__device__ __forceinline__ u16 f2bf(float f){
  union { float f; unsigned int i; } v; v.f = f;
  unsigned int r = v.i + 0x7fffu + ((v.i >> 16) & 1u);  // RTNE
  return (u16)(r >> 16);
}

// ---------------- fp32 -> bf16 convert (vectorized) ----------------
__global__ void k_cvt(const float* __restrict__ s, u16* __restrict__ d, long n4){
  long i = (long)blockIdx.x * blockDim.x + threadIdx.x;
  long st = (long)gridDim.x * blockDim.x;
  for (long j = i; j < n4; j += st){
    float4 v = ((const float4*)s)[j];
    ushort4 o;
    o.x = f2bf(v.x); o.y = f2bf(v.y); o.z = f2bf(v.z); o.w = f2bf(v.w);
    ((ushort4*)d)[j] = o;
  }
}

__global__ void k_bias(const float* __restrict__ a, const float* __restrict__ b,
                       float* __restrict__ o, int n){
  int i = blockIdx.x * 256 + threadIdx.x;
  if (i < n) o[i] = a[i] + b[i];
}

// ---------------- input GEMM: pre[s][b][g] = A[m=b*512+s][:] . W[g][:] + bias[g] ----------------
// A [M][1024] bf16, W [4096][1024] bf16, pre [512][64][4096] bf16.
// 128x128 tile, BK=64, 4 waves (2x2, 64x64 each), reg-staged LDS with XOR swizzle.
__launch_bounds__(256, 2)
__global__ void k_gemm_pre(const u16* __restrict__ A, const u16* __restrict__ W,
                           const float* __restrict__ bias, u16* __restrict__ pre)
{
  __shared__ u16 As[128 * 64], Bs[128 * 64];
  const int tid = threadIdx.x;
  const int lane = tid & 63;
  const int w = tid >> 6, wm = w >> 1, wn = w & 1;
  const long bm0 = (long)blockIdx.x * 128;
  const int bn0 = blockIdx.y * 128;

  const f32x4 z = {0.f, 0.f, 0.f, 0.f};
  f32x4 acc[4][4];
  #pragma unroll
  for (int mi = 0; mi < 4; ++mi)
    #pragma unroll
    for (int ni = 0; ni < 4; ++ni) acc[mi][ni] = z;

  for (int kt = 0; kt < 1024; kt += 64){
    #pragma unroll
    for (int p = 0; p < 4; ++p){
      int ch = p * 256 + tid;
      int r = ch >> 3, c16 = ch & 7;  // 8 x 16B chunks per 128B row
      uint4 va = *(const uint4*)(A + (bm0 + r) * 1024 + kt + c16 * 8);
      *(uint4*)((char*)As + r * 128 + ((c16 * 16) ^ ((r & 7) << 4))) = va;
      uint4 vb = *(const uint4*)(W + ((long)(bn0 + r)) * 1024 + kt + c16 * 8);
      *(uint4*)((char*)Bs + r * 128 + ((c16 * 16) ^ ((r & 7) << 4))) = vb;
    }
    __syncthreads();
    #pragma unroll
    for (int ks = 0; ks < 2; ++ks){
      int kb = ks * 64 + ((lane >> 4) * 16);
      bf16x8 af[4], bfr[4];
      #pragma unroll
      for (int mi = 0; mi < 4; ++mi){
        int r = wm * 64 + mi * 16 + (lane & 15);
        af[mi] = *(bf16x8*)((char*)As + r * 128 + (kb ^ ((r & 7) << 4)));
      }
      #pragma unroll
      for (int ni = 0; ni < 4; ++ni){
        int r = wn * 64 + ni * 16 + (lane & 15);
        bfr[ni] = *(bf16x8*)((char*)Bs + r * 128 + (kb ^ ((r & 7) << 4)));
      }
      #pragma unroll
      for (int mi = 0; mi < 4; ++mi)
        #pragma unroll
        for (int ni = 0; ni < 4; ++ni)
          acc[mi][ni] = __builtin_amdgcn_mfma_f32_16x16x32_bf16(af[mi], bfr[ni], acc[mi][ni], 0, 0, 0);
    }
    __syncthreads();
  }
  // epilogue: +bias, bf16, row remap m=(b*512+s) -> (s*64+b)
  const int fq = lane >> 4, fr = lane & 15;
  #pragma unroll
  for (int ni = 0; ni < 4; ++ni){
    int n = bn0 + wn * 64 + ni * 16 + fr;
    float bv = bias[n];
    #pragma unroll
    for (int mi = 0; mi < 4; ++mi){
      #pragma unroll
      for (int j = 0; j < 4; ++j){
        long m = bm0 + wm * 64 + mi * 16 + fq * 4 + j;
        int s = (int)(m & 511), b = (int)(m >> 9);
        pre[((long)(s * 64 + b) << 12) + n] = f2bf(acc[mi][ni][j] + bv);
      }
    }
  }
}

// ---------------- persistent LSTM scan (one layer) ----------------
// 256 blocks x 256 thr. Block = (batch-half bg of 32) x (j-slice js of 8)
// -> owns 32 gate rows {q*1024 + js*8 + 0..8, q=0..3} and cell state for
// (32 batch x 8 j). Wh slice LDS-resident (64KB). h broadcast via global
// double-buffered bf16 hbuf + flag barrier over the 128 same-bg blocks.
__launch_bounds__(256, 1)
__global__ void lstm_scan(const u16* __restrict__ pre,   // [512][64][4096] bf16
                          const u16* __restrict__ Wh,    // [4096][1024] bf16
                          u16* __restrict__ hbuf,        // [2][64][1024] bf16 (zeroed)
                          int* __restrict__ flags,       // [256] (zeroed)
                          u16* __restrict__ hs_bf,       // [64][512][1024] bf16 (layer 0 out)
                          float* __restrict__ out,       // d_out base
                          int layer)
{
  extern __shared__ char smem[];   // [0,64K) WhS, [64K,128K) hS, [128K,144K) gatesS
  float* gatesS = (float*)(smem + 131072);

  const int tid = threadIdx.x;
  const int lane = tid & 63;
  const int w = tid >> 6;
  const int bid = blockIdx.x;
  const int bg = bid >> 7;      // batch half
  const int js = bid & 127;     // j-slice

  // Wh slice -> LDS once, per-wave k-quarter (wave only ever reads its own quarter),
  // XOR-swizzled (G4: row-stride 2048B is a 16-way conflict otherwise).
  for (int p = 0; p < 16; ++p){
    int c = p * 64 + lane;             // [0,1024) chunks of this wave's quarter
    int r = c >> 5;                    // local row [0,32)
    int k16 = w * 32 + (c & 31);       // 16B chunk in row [0,128)
    int grow = ((r >> 3) << 10) + js * 8 + (r & 7);   // global gate row
    uint4 v = *(const uint4*)(Wh + ((long)grow << 10) + k16 * 8);
    *(uint4*)(smem + r * 2048 + ((k16 * 16) ^ ((r & 7) << 4))) = v;
  }

  float c_reg = 0.f;                // cell state, fp32, block-local
  const int m_t = tid >> 3;         // [0,32) local batch row
  const int jj = tid & 7;           // [0,8)  local j
  const int flag_base = bg * 128;

  for (int t = 0; t < 512; ++t){
    if (t > 0){
      if (tid < 128){
        while (__hip_atomic_load(&flags[flag_base + tid], __ATOMIC_RELAXED, SCOPE_AGENT) < t)
          __builtin_amdgcn_s_sleep(1);
      }
      __syncthreads();
      __threadfence();   // agent acquire: invalidate stale cached h lines (cross-XCD)
    }
    // stage h_t (my batch half) -> LDS, per-wave k-quarter, swizzled
    const u16* hread = hbuf + ((t & 1) << 16);
    for (int p = 0; p < 16; ++p){
      int c = p * 64 + lane;
      int r = c >> 5;
      int k16 = w * 32 + (c & 31);
      uint4 v = *(const uint4*)(hread + ((bg * 32 + r) << 10) + k16 * 8);
      *(uint4*)(smem + 65536 + r * 2048 + ((k16 * 16) ^ ((r & 7) << 4))) = v;
    }
    // gates partial GEMM: wave w covers K range [w*256, (w+1)*256) (ks = k/32)
    f32x4 acc00 = {0.f,0.f,0.f,0.f}, acc01 = {0.f,0.f,0.f,0.f};
    f32x4 acc10 = {0.f,0.f,0.f,0.f}, acc11 = {0.f,0.f,0.f,0.f};
    #pragma unroll
    for (int ks = 0; ks < 8; ++ks){
      int kb = (w * 8 + ks) * 64 + ((lane >> 4) * 16);
      int r0 = lane & 15, r1 = 16 + (lane & 15);
      bf16x8 a0 = *(bf16x8*)(smem + 65536 + r0 * 2048 + (kb ^ ((r0 & 7) << 4)));
      bf16x8 a1 = *(bf16x8*)(smem + 65536 + r1 * 2048 + (kb ^ ((r1 & 7) << 4)));
      bf16x8 b0 = *(bf16x8*)(smem + r0 * 2048 + (kb ^ ((r0 & 7) << 4)));
      bf16x8 b1 = *(bf16x8*)(smem + r1 * 2048 + (kb ^ ((r1 & 7) << 4)));
      acc00 = __builtin_amdgcn_mfma_f32_16x16x32_bf16(a0, b0, acc00, 0, 0, 0);
      acc01 = __builtin_amdgcn_mfma_f32_16x16x32_bf16(a0, b1, acc01, 0, 0, 0);
      acc10 = __builtin_amdgcn_mfma_f32_16x16x32_bf16(a1, b0, acc10, 0, 0, 0);
      acc11 = __builtin_amdgcn_mfma_f32_16x16x32_bf16(a1, b1, acc11, 0, 0, 0);
    }
    {  // partial gates -> LDS (C/D map: row=(lane>>4)*4+j, col=lane&15 — m89)
      int fq = lane >> 4, fr = lane & 15;
      #pragma unroll
      for (int j = 0; j < 4; ++j){
        int row0 = fq * 4 + j, row1 = 16 + fq * 4 + j;
        gatesS[(w * 32 + row0) * 32 + fr]      = acc00[j];
        gatesS[(w * 32 + row0) * 32 + 16 + fr] = acc01[j];
        gatesS[(w * 32 + row1) * 32 + fr]      = acc10[j];
        gatesS[(w * 32 + row1) * 32 + 16 + fr] = acc11[j];
      }
    }
    __syncthreads();
    // elementwise LSTM cell: thread owns (m_t, jj)
    long prebase = (long)t * 262144 + ((long)(bg * 32 + m_t) << 12) + js * 8 + jj;
    float gv[4];
    #pragma unroll
    for (int q = 0; q < 4; ++q){
      float s = bf2f(pre[prebase + (q << 10)]);
      #pragma unroll
      for (int w2 = 0; w2 < 4; ++w2) s += gatesS[(w2 * 32 + m_t) * 32 + q * 8 + jj];
      gv[q] = s;
    }
    float ig = 1.f / (1.f + expf(-gv[0]));
    float fg = 1.f / (1.f + expf(-gv[1]));
    float gg = tanhf(gv[2]);
    float og = 1.f / (1.f + expf(-gv[3]));
    c_reg = fg * c_reg + ig * gg;
    float h = og * tanhf(c_reg);
    u16 hb = f2bf(h);
    int hidx = ((bg * 32 + m_t) << 10) + js * 8 + jj;
    u16* hwrite = hbuf + (((t + 1) & 1) << 16);
    hwrite[hidx] = hb;
    if (layer == 0){
      hs_bf[(((long)(bg * 32 + m_t)) * 512 + t) * 1024 + js * 8 + jj] = hb;
    } else {
      out[(((long)(bg * 32 + m_t)) * 512 + t) * 1024 + js * 8 + jj] = h;
    }
    if (t == 511){
      float* hn = out + 33554432 + layer * 65536;
      float* cn = out + 33554432 + 131072 + layer * 65536;
      hn[hidx] = h;
      cn[hidx] = c_reg;
    }
    __syncthreads();                 // drains all threads' h stores (vmcnt 0)
    if (tid == 0){
      __threadfence();               // agent release: make h visible cross-XCD
      __hip_atomic_store(&flags[bid], t + 1, __ATOMIC_RELAXED, SCOPE_AGENT);
    }
  }
}

extern "C" void kernel_launch(void* const* d_in, const int* in_sizes, int n_in,
                              void* d_out, int out_size, void* d_ws, size_t ws_size,
                              hipStream_t stream)
{
  const float* x   = (const float*)d_in[0];
  const float* Wi0 = (const float*)d_in[1];
  const float* Wh0 = (const float*)d_in[2];
  const float* bi0 = (const float*)d_in[3];
  const float* bh0 = (const float*)d_in[4];
  const float* Wi1 = (const float*)d_in[5];
  const float* Wh1 = (const float*)d_in[6];
  const float* bi1 = (const float*)d_in[7];
  const float* bh1 = (const float*)d_in[8];
  float* out = (float*)d_out;
  char* ws = (char*)d_ws;

  size_t o = 0;
  u16* pre   = (u16*)(ws + o); o += (size_t)268435456;   // [512][64][4096] bf16 (reused L0/L1)
  u16* xbf   = (u16*)(ws + o); o += 67108864;            // x bf16, then reused as hs0 bf16
  u16* Wi0b  = (u16*)(ws + o); o += 8388608;
  u16* Wh0b  = (u16*)(ws + o); o += 8388608;
  u16* Wi1b  = (u16*)(ws + o); o += 8388608;
  u16* Wh1b  = (u16*)(ws + o); o += 8388608;
  float* bias0 = (float*)(ws + o); o += 16384;
  float* bias1 = (float*)(ws + o); o += 16384;
  u16* hbuf  = (u16*)(ws + o); o += 262144;              // [2][64][1024] bf16
  int* flags = (int*)(ws + o); o += 1024;                // [256]

  // bf16 conversions + bias sums
  k_cvt<<<dim3(2048), dim3(256), 0, stream>>>(x,   xbf,  33554432L / 4);
  k_cvt<<<dim3(512),  dim3(256), 0, stream>>>(Wi0, Wi0b, 4194304L / 4);
  k_cvt<<<dim3(512),  dim3(256), 0, stream>>>(Wh0, Wh0b, 4194304L / 4);
  k_cvt<<<dim3(512),  dim3(256), 0, stream>>>(Wi1, Wi1b, 4194304L / 4);
  k_cvt<<<dim3(512),  dim3(256), 0, stream>>>(Wh1, Wh1b, 4194304L / 4);
  k_bias<<<dim3(16), dim3(256), 0, stream>>>(bi0, bh0, bias0, 4096);
  k_bias<<<dim3(16), dim3(256), 0, stream>>>(bi1, bh1, bias1, 4096);

  hipFuncSetAttribute((const void*)lstm_scan,
                      hipFuncAttributeMaxDynamicSharedMemorySize, 147456);

  int layer0 = 0, layer1 = 1;

  // ---- layer 0 ----
  k_gemm_pre<<<dim3(256, 32), dim3(256), 0, stream>>>(xbf, Wi0b, bias0, pre);
  hipMemsetAsync(hbuf, 0, 262144 + 1024, stream);        // hbuf + flags (contiguous)
  {
    void* args[] = { &pre, &Wh0b, &hbuf, &flags, &xbf, &out, &layer0 };
    hipLaunchCooperativeKernel((const void*)lstm_scan, dim3(256), dim3(256),
                               args, 147456, stream);
  }

  // ---- layer 1 (xbf now holds hs0 bf16) ----
  k_gemm_pre<<<dim3(256, 32), dim3(256), 0, stream>>>(xbf, Wi1b, bias1, pre);
  hipMemsetAsync(hbuf, 0, 262144 + 1024, stream);
  {
    void* args[] = { &pre, &Wh1b, &hbuf, &flags, &xbf, &out, &layer1 };
    hipLaunchCooperativeKernel((const void*)lstm_scan, dim3(256), dim3(256),
                               args, 147456, stream);
  }
}

// Round 2
// 5198.475 us; speedup vs baseline: 6.2495x; 6.2495x over previous
//
#include <hip/hip_runtime.h>
#include <hip/hip_bf16.h>

typedef unsigned short u16;
typedef unsigned int u32;
typedef __attribute__((ext_vector_type(8))) short bf16x8;   // 8 bf16 (4 VGPRs)
typedef __attribute__((ext_vector_type(4))) float f32x4;    // MFMA accumulator
typedef __attribute__((ext_vector_type(4))) u32 u32x4;      // asm-load tuple

#define SCOPE_AGENT __HIP_MEMORY_SCOPE_AGENT

__device__ __forceinline__ float bf2f(u16 u){
  union { unsigned int i; float f; } v; v.i = ((unsigned int)u) << 16; return v.f;
}
__device__ __forceinline__ u16 f2bf(float f){
  union { float f; unsigned int i; } v; v.f = f;
  unsigned int r = v.i + 0x7fffu + ((v.i >> 16) & 1u);  // RTNE
  return (u16)(r >> 16);
}

// ---------------- fp32 -> bf16 convert (vectorized) ----------------
__global__ void k_cvt(const float* __restrict__ s, u16* __restrict__ d, long n4){
  long i = (long)blockIdx.x * blockDim.x + threadIdx.x;
  long st = (long)gridDim.x * blockDim.x;
  for (long j = i; j < n4; j += st){
    float4 v = ((const float4*)s)[j];
    ushort4 o;
    o.x = f2bf(v.x); o.y = f2bf(v.y); o.z = f2bf(v.z); o.w = f2bf(v.w);
    ((ushort4*)d)[j] = o;
  }
}

__global__ void k_bias(const float* __restrict__ a, const float* __restrict__ b,
                       float* __restrict__ o, int n){
  int i = blockIdx.x * 256 + threadIdx.x;
  if (i < n) o[i] = a[i] + b[i];
}

// ---------------- input GEMM: pre[s][b][g] = A[m=b*512+s][:] . W[g][:] + bias[g] ----------------
__launch_bounds__(256, 2)
__global__ void k_gemm_pre(const u16* __restrict__ A, const u16* __restrict__ W,
                           const float* __restrict__ bias, u16* __restrict__ pre)
{
  __shared__ u16 As[128 * 64], Bs[128 * 64];
  const int tid = threadIdx.x;
  const int lane = tid & 63;
  const int w = tid >> 6, wm = w >> 1, wn = w & 1;
  const long bm0 = (long)blockIdx.x * 128;
  const int bn0 = blockIdx.y * 128;

  const f32x4 z = {0.f, 0.f, 0.f, 0.f};
  f32x4 acc[4][4];
  #pragma unroll
  for (int mi = 0; mi < 4; ++mi)
    #pragma unroll
    for (int ni = 0; ni < 4; ++ni) acc[mi][ni] = z;

  for (int kt = 0; kt < 1024; kt += 64){
    #pragma unroll
    for (int p = 0; p < 4; ++p){
      int ch = p * 256 + tid;
      int r = ch >> 3, c16 = ch & 7;
      uint4 va = *(const uint4*)(A + (bm0 + r) * 1024 + kt + c16 * 8);
      *(uint4*)((char*)As + r * 128 + ((c16 * 16) ^ ((r & 7) << 4))) = va;
      uint4 vb = *(const uint4*)(W + ((long)(bn0 + r)) * 1024 + kt + c16 * 8);
      *(uint4*)((char*)Bs + r * 128 + ((c16 * 16) ^ ((r & 7) << 4))) = vb;
    }
    __syncthreads();
    #pragma unroll
    for (int ks = 0; ks < 2; ++ks){
      int kb = ks * 64 + ((lane >> 4) * 16);
      bf16x8 af[4], bfr[4];
      #pragma unroll
      for (int mi = 0; mi < 4; ++mi){
        int r = wm * 64 + mi * 16 + (lane & 15);
        af[mi] = *(bf16x8*)((char*)As + r * 128 + (kb ^ ((r & 7) << 4)));
      }
      #pragma unroll
      for (int ni = 0; ni < 4; ++ni){
        int r = wn * 64 + ni * 16 + (lane & 15);
        bfr[ni] = *(bf16x8*)((char*)Bs + r * 128 + (kb ^ ((r & 7) << 4)));
      }
      #pragma unroll
      for (int mi = 0; mi < 4; ++mi)
        #pragma unroll
        for (int ni = 0; ni < 4; ++ni)
          acc[mi][ni] = __builtin_amdgcn_mfma_f32_16x16x32_bf16(af[mi], bfr[ni], acc[mi][ni], 0, 0, 0);
    }
    __syncthreads();
  }
  const int fq = lane >> 4, fr = lane & 15;
  #pragma unroll
  for (int ni = 0; ni < 4; ++ni){
    int n = bn0 + wn * 64 + ni * 16 + fr;
    float bv = bias[n];
    #pragma unroll
    for (int mi = 0; mi < 4; ++mi){
      #pragma unroll
      for (int j = 0; j < 4; ++j){
        long m = bm0 + wm * 64 + mi * 16 + fq * 4 + j;
        int s = (int)(m & 511), b = (int)(m >> 9);
        pre[((long)(s * 64 + b) << 12) + n] = f2bf(acc[mi][ni][j] + bv);
      }
    }
  }
}

// ---------------- persistent LSTM scan (one layer) ----------------
// Fence-free protocol: h communicated via agent-scope (sc0 sc1) write-through
// stores + agent-scope L3-direct loads; flags relaxed agent atomics on padded
// 128B lines. No buffer_wbl2 / buffer_inv anywhere in the step loop.
__launch_bounds__(256, 1)
__global__ void lstm_scan(const u16* __restrict__ pre,   // [512][64][4096] bf16
                          const u16* __restrict__ Wh,    // [4096][1024] bf16
                          u16* __restrict__ hbuf,        // [2][64][1024] bf16 (zeroed)
                          int* __restrict__ flags,       // [256*32] padded (zeroed)
                          u16* __restrict__ hs_bf,       // [64][512][1024] bf16 (layer 0 out)
                          float* __restrict__ out,       // d_out base
                          int layer)
{
  extern __shared__ char smem[];   // [0,64K) WhS, [64K,128K) hS, [128K,144K) gatesS
  float* gatesS = (float*)(smem + 131072);

  const int tid = threadIdx.x;
  const int lane = tid & 63;
  const int w = tid >> 6;
  const int bid = blockIdx.x;
  const int bg = bid >> 7;      // batch half
  const int js = bid & 127;     // j-slice

  // Wh slice -> LDS once (per-wave k-quarter, XOR-swizzled)
  for (int p = 0; p < 16; ++p){
    int c = p * 64 + lane;
    int r = c >> 5;
    int k16 = w * 32 + (c & 31);
    int grow = ((r >> 3) << 10) + js * 8 + (r & 7);
    uint4 v = *(const uint4*)(Wh + ((long)grow << 10) + k16 * 8);
    *(uint4*)(smem + r * 2048 + ((k16 * 16) ^ ((r & 7) << 4))) = v;
  }

  float c_reg = 0.f;
  const int m_t = tid >> 3;         // [0,32) local batch row
  const int jj = tid & 7;           // [0,8)  local j
  const int flag_base = bg * 128;
  const long prebase0 = ((long)(bg * 32 + m_t) << 12) + js * 8 + jj;

  for (int t = 0; t < 512; ++t){
    // prefetch this step's pre values (no cross-block dependency) before poll
    u16 pv[4];
    {
      const u16* p0 = pre + (long)t * 262144 + prebase0;
      #pragma unroll
      for (int q = 0; q < 4; ++q) pv[q] = p0[q << 10];
    }

    f32x4 acc00 = {0.f,0.f,0.f,0.f}, acc01 = {0.f,0.f,0.f,0.f};
    f32x4 acc10 = {0.f,0.f,0.f,0.f}, acc11 = {0.f,0.f,0.f,0.f};

    if (t > 0){
      if (tid < 128){
        while (__hip_atomic_load(&flags[(flag_base + tid) * 32], __ATOMIC_RELAXED, SCOPE_AGENT) < t)
          __builtin_amdgcn_s_sleep(2);
      }
      __syncthreads();

      // stage h_t (my batch half) -> LDS via agent-scope L3-direct loads,
      // batched: 16 async dwordx4 loads, ONE vmcnt(0), then LDS writes.
      const u32* h32 = (const u32*)(hbuf + ((t & 1) << 16));
      u32x4 hv[16];
      #pragma unroll
      for (int p = 0; p < 16; ++p){
        int c = p * 64 + lane;
        int r = c >> 5;
        int k16 = w * 32 + (c & 31);
        const u32* src = h32 + (long)(bg * 32 + r) * 512 + k16 * 4;
        asm volatile("global_load_dwordx4 %0, %1, off sc0 sc1"
                     : "=v"(hv[p]) : "v"(src) : "memory");
      }
      asm volatile("s_waitcnt vmcnt(0)" ::: "memory");
      __builtin_amdgcn_sched_barrier(0);
      #pragma unroll
      for (int p = 0; p < 16; ++p){
        int c = p * 64 + lane;
        int r = c >> 5;
        int k16 = w * 32 + (c & 31);
        *(u32x4*)(smem + 65536 + r * 2048 + ((k16 * 16) ^ ((r & 7) << 4))) = hv[p];
      }

      // gates partial GEMM: wave w covers its K quarter
      #pragma unroll
      for (int ks = 0; ks < 8; ++ks){
        int kb = (w * 8 + ks) * 64 + ((lane >> 4) * 16);
        int r0 = lane & 15, r1 = 16 + (lane & 15);
        bf16x8 a0 = *(bf16x8*)(smem + 65536 + r0 * 2048 + (kb ^ ((r0 & 7) << 4)));
        bf16x8 a1 = *(bf16x8*)(smem + 65536 + r1 * 2048 + (kb ^ ((r1 & 7) << 4)));
        bf16x8 b0 = *(bf16x8*)(smem + r0 * 2048 + (kb ^ ((r0 & 7) << 4)));
        bf16x8 b1 = *(bf16x8*)(smem + r1 * 2048 + (kb ^ ((r1 & 7) << 4)));
        acc00 = __builtin_amdgcn_mfma_f32_16x16x32_bf16(a0, b0, acc00, 0, 0, 0);
        acc01 = __builtin_amdgcn_mfma_f32_16x16x32_bf16(a0, b1, acc01, 0, 0, 0);
        acc10 = __builtin_amdgcn_mfma_f32_16x16x32_bf16(a1, b0, acc10, 0, 0, 0);
        acc11 = __builtin_amdgcn_mfma_f32_16x16x32_bf16(a1, b1, acc11, 0, 0, 0);
      }
    }

    {  // partial gates -> LDS (C/D map: row=(lane>>4)*4+j, col=lane&15)
      int fq = lane >> 4, fr = lane & 15;
      #pragma unroll
      for (int j = 0; j < 4; ++j){
        int row0 = fq * 4 + j, row1 = 16 + fq * 4 + j;
        gatesS[(w * 32 + row0) * 32 + fr]      = acc00[j];
        gatesS[(w * 32 + row0) * 32 + 16 + fr] = acc01[j];
        gatesS[(w * 32 + row1) * 32 + fr]      = acc10[j];
        gatesS[(w * 32 + row1) * 32 + 16 + fr] = acc11[j];
      }
    }
    __syncthreads();

    // elementwise LSTM cell: thread owns (m_t, jj)
    float gv[4];
    #pragma unroll
    for (int q = 0; q < 4; ++q){
      float s = bf2f(pv[q]);
      #pragma unroll
      for (int w2 = 0; w2 < 4; ++w2) s += gatesS[(w2 * 32 + m_t) * 32 + q * 8 + jj];
      gv[q] = s;
    }
    float ig = 1.f / (1.f + expf(-gv[0]));
    float fg = 1.f / (1.f + expf(-gv[1]));
    float gg = tanhf(gv[2]);
    float og = 1.f / (1.f + expf(-gv[3]));
    c_reg = fg * c_reg + ig * gg;
    float h = og * tanhf(c_reg);
    u16 hb = f2bf(h);
    int hidx = ((bg * 32 + m_t) << 10) + js * 8 + jj;

    // pack pairs and write-through to L3 (agent scope) for next step's readers
    float h_other = __shfl_xor(h, 1);
    u32 packed = (u32)hb | ((u32)f2bf(h_other) << 16);
    if (!(tid & 1)){
      u32* hw32 = (u32*)(hbuf + (((t + 1) & 1) << 16));
      __hip_atomic_store(&hw32[hidx >> 1], packed, __ATOMIC_RELAXED, SCOPE_AGENT);
    }

    if (layer == 0){
      hs_bf[(((long)(bg * 32 + m_t)) * 512 + t) * 1024 + js * 8 + jj] = hb;
    } else {
      out[(((long)(bg * 32 + m_t)) * 512 + t) * 1024 + js * 8 + jj] = h;
    }
    if (t == 511){
      float* hn = out + 33554432 + layer * 65536;
      float* cn = out + 33554432 + 131072 + layer * 65536;
      hn[hidx] = h;
      cn[hidx] = c_reg;
    }
    __syncthreads();                 // drains vmcnt(0): h stores visible at L3
    if (tid == 0){
      __hip_atomic_store(&flags[bid * 32], t + 1, __ATOMIC_RELAXED, SCOPE_AGENT);
    }
  }
}

extern "C" void kernel_launch(void* const* d_in, const int* in_sizes, int n_in,
                              void* d_out, int out_size, void* d_ws, size_t ws_size,
                              hipStream_t stream)
{
  const float* x   = (const float*)d_in[0];
  const float* Wi0 = (const float*)d_in[1];
  const float* Wh0 = (const float*)d_in[2];
  const float* bi0 = (const float*)d_in[3];
  const float* bh0 = (const float*)d_in[4];
  const float* Wi1 = (const float*)d_in[5];
  const float* Wh1 = (const float*)d_in[6];
  const float* bi1 = (const float*)d_in[7];
  const float* bh1 = (const float*)d_in[8];
  float* out = (float*)d_out;
  char* ws = (char*)d_ws;

  size_t o = 0;
  u16* pre   = (u16*)(ws + o); o += (size_t)268435456;   // [512][64][4096] bf16
  u16* xbf   = (u16*)(ws + o); o += 67108864;            // x bf16, then hs0 bf16
  u16* Wi0b  = (u16*)(ws + o); o += 8388608;
  u16* Wh0b  = (u16*)(ws + o); o += 8388608;
  u16* Wi1b  = (u16*)(ws + o); o += 8388608;
  u16* Wh1b  = (u16*)(ws + o); o += 8388608;
  float* bias0 = (float*)(ws + o); o += 16384;
  float* bias1 = (float*)(ws + o); o += 16384;
  u16* hbuf  = (u16*)(ws + o); o += 262144;              // [2][64][1024] bf16
  int* flags = (int*)(ws + o); o += 32768;               // [256*32] padded

  k_cvt<<<dim3(2048), dim3(256), 0, stream>>>(x,   xbf,  33554432L / 4);
  k_cvt<<<dim3(512),  dim3(256), 0, stream>>>(Wi0, Wi0b, 4194304L / 4);
  k_cvt<<<dim3(512),  dim3(256), 0, stream>>>(Wh0, Wh0b, 4194304L / 4);
  k_cvt<<<dim3(512),  dim3(256), 0, stream>>>(Wi1, Wh1 ? Wi1b : Wi1b, 4194304L / 4);
  k_cvt<<<dim3(512),  dim3(256), 0, stream>>>(Wh1, Wh1b, 4194304L / 4);
  k_bias<<<dim3(16), dim3(256), 0, stream>>>(bi0, bh0, bias0, 4096);
  k_bias<<<dim3(16), dim3(256), 0, stream>>>(bi1, bh1, bias1, 4096);

  hipFuncSetAttribute((const void*)lstm_scan,
                      hipFuncAttributeMaxDynamicSharedMemorySize, 147456);

  int layer0 = 0, layer1 = 1;

  // ---- layer 0 ----
  k_gemm_pre<<<dim3(256, 32), dim3(256), 0, stream>>>(xbf, Wi0b, bias0, pre);
  hipMemsetAsync(hbuf, 0, 262144 + 32768, stream);       // hbuf + padded flags
  {
    void* args[] = { &pre, &Wh0b, &hbuf, &flags, &xbf, &out, &layer0 };
    hipLaunchCooperativeKernel((const void*)lstm_scan, dim3(256), dim3(256),
                               args, 147456, stream);
  }

  // ---- layer 1 (xbf now holds hs0 bf16) ----
  k_gemm_pre<<<dim3(256, 32), dim3(256), 0, stream>>>(xbf, Wi1b, bias1, pre);
  hipMemsetAsync(hbuf, 0, 262144 + 32768, stream);
  {
    void* args[] = { &pre, &Wh1b, &hbuf, &flags, &xbf, &out, &layer1 };
    hipLaunchCooperativeKernel((const void*)lstm_scan, dim3(256), dim3(256),
                               args, 147456, stream);
  }
}